// Round 1
// baseline (42.246 us; speedup 1.0000x reference)
//
#include <hip/hip_runtime.h>

// Problem constants (from reference): x (8,4096,3,256) f32, w (1,3584,1,1) f32,
// out (8,3584,3,256) f32. KERNELS = [2,4,8] for every channel; 2048+1024+512 = 3584 = MAX_LEN.
#define B_   8
#define T_   4096
#define C_   3
#define D_   256
#define ML_  3584

// One thread owns (b, c, d4-quad) and an 8-row input window g (g in [0,512)).
// It reads 8 float4s (rows g*8 .. g*8+7) and writes 7 float4 outputs:
//   k=2: t = g*4 + i        (i=0..3)
//   k=4: t = 2048 + g*2 + i (i=0..1)
//   k=8: t = 3072 + g
__global__ __launch_bounds__(256) void multi_scale_kernel(
    const float4* __restrict__ x, const float* __restrict__ w, float4* __restrict__ out)
{
    const int id = blockIdx.x * 256 + threadIdx.x;
    const int d4 = id & 63;            // float4 index within 256-float row slice
    const int c  = (id >> 6) % 3;
    const int g  = (id / 192) & 511;   // 8-row window index
    const int b  = id / (192 * 512);

    const int rs = (C_ * D_) / 4;      // row stride in float4 units = 192

    const float4* xb = x + ((size_t)b * T_ + (size_t)g * 8) * rs + c * (D_ / 4) + d4;

    float4 a[8];
#pragma unroll
    for (int j = 0; j < 8; ++j) a[j] = xb[(size_t)j * rs];

    float4 s2[4], m2[4];
#pragma unroll
    for (int i = 0; i < 4; ++i) {
        s2[i].x = a[2*i].x + a[2*i+1].x; m2[i].x = fmaxf(a[2*i].x, a[2*i+1].x);
        s2[i].y = a[2*i].y + a[2*i+1].y; m2[i].y = fmaxf(a[2*i].y, a[2*i+1].y);
        s2[i].z = a[2*i].z + a[2*i+1].z; m2[i].z = fmaxf(a[2*i].z, a[2*i+1].z);
        s2[i].w = a[2*i].w + a[2*i+1].w; m2[i].w = fmaxf(a[2*i].w, a[2*i+1].w);
    }
    float4 s4[2], m4[2];
#pragma unroll
    for (int i = 0; i < 2; ++i) {
        s4[i].x = s2[2*i].x + s2[2*i+1].x; m4[i].x = fmaxf(m2[2*i].x, m2[2*i+1].x);
        s4[i].y = s2[2*i].y + s2[2*i+1].y; m4[i].y = fmaxf(m2[2*i].y, m2[2*i+1].y);
        s4[i].z = s2[2*i].z + s2[2*i+1].z; m4[i].z = fmaxf(m2[2*i].z, m2[2*i+1].z);
        s4[i].w = s2[2*i].w + s2[2*i+1].w; m4[i].w = fmaxf(m2[2*i].w, m2[2*i+1].w);
    }
    float4 s8, m8;
    s8.x = s4[0].x + s4[1].x; m8.x = fmaxf(m4[0].x, m4[1].x);
    s8.y = s4[0].y + s4[1].y; m8.y = fmaxf(m4[0].y, m4[1].y);
    s8.z = s4[0].z + s4[1].z; m8.z = fmaxf(m4[0].z, m4[1].z);
    s8.w = s4[0].w + s4[1].w; m8.w = fmaxf(m4[0].w, m4[1].w);

    float4* ob = out + (size_t)b * ML_ * rs + c * (D_ / 4) + d4;

#pragma unroll
    for (int i = 0; i < 4; ++i) {
        const int t = g * 4 + i;
        const float wv = w[t];
        const float iw = 1.0f - wv;
        float4 r;
        r.x = s2[i].x * 0.5f * wv + m2[i].x * iw;
        r.y = s2[i].y * 0.5f * wv + m2[i].y * iw;
        r.z = s2[i].z * 0.5f * wv + m2[i].z * iw;
        r.w = s2[i].w * 0.5f * wv + m2[i].w * iw;
        ob[(size_t)t * rs] = r;
    }
#pragma unroll
    for (int i = 0; i < 2; ++i) {
        const int t = 2048 + g * 2 + i;
        const float wv = w[t];
        const float iw = 1.0f - wv;
        float4 r;
        r.x = s4[i].x * 0.25f * wv + m4[i].x * iw;
        r.y = s4[i].y * 0.25f * wv + m4[i].y * iw;
        r.z = s4[i].z * 0.25f * wv + m4[i].z * iw;
        r.w = s4[i].w * 0.25f * wv + m4[i].w * iw;
        ob[(size_t)t * rs] = r;
    }
    {
        const int t = 3072 + g;
        const float wv = w[t];
        const float iw = 1.0f - wv;
        float4 r;
        r.x = s8.x * 0.125f * wv + m8.x * iw;
        r.y = s8.y * 0.125f * wv + m8.y * iw;
        r.z = s8.z * 0.125f * wv + m8.z * iw;
        r.w = s8.w * 0.125f * wv + m8.w * iw;
        ob[(size_t)t * rs] = r;
    }
}

extern "C" void kernel_launch(void* const* d_in, const int* in_sizes, int n_in,
                              void* d_out, int out_size, void* d_ws, size_t ws_size,
                              hipStream_t stream) {
    const float4* x = (const float4*)d_in[0];
    const float*  w = (const float*)d_in[1];
    float4* out = (float4*)d_out;

    // total threads = B * (T/8) * C * (D/4) = 8*512*3*64 = 786432 = 3072 blocks * 256
    const int nthreads = B_ * (T_ / 8) * C_ * (D_ / 4);
    const int blocks = nthreads / 256;
    multi_scale_kernel<<<blocks, 256, 0, stream>>>(x, w, out);
}

// Round 2
// 32.858 us; speedup vs baseline: 1.2857x; 1.2857x over previous
//
#include <hip/hip_runtime.h>

// Problem constants: x (8,4096,3,256) f32, w (1,3584,1,1) f32, out (8,3584,3,256) f32.
// KERNELS = [2,4,8] per channel; 2048+1024+512 = 3584 = MAX_LEN (no pad/trunc needed).
#define B_   8
#define T_   4096
#define C_   3
#define D_   256
#define ML_  3584

typedef float v4 __attribute__((ext_vector_type(4)));

// One thread owns (b, c, d4-quad) and an 8-row input window g in [0,512).
// Reads 8 float4s once; writes 7 pooled outputs (4x k=2, 2x k=4, 1x k=8).
__global__ __launch_bounds__(256) void multi_scale_kernel(
    const v4* __restrict__ x, const float* __restrict__ w, v4* __restrict__ out)
{
    const int id = blockIdx.x * 256 + threadIdx.x;
    const int d4 = id & 63;            // float4 index within 256-float row slice
    const int c  = (id >> 6) % 3;
    const int g  = (id / 192) & 511;   // 8-row window index (wave-uniform)
    const int b  = id / (192 * 512);

    const int rs = (C_ * D_) / 4;      // row stride in float4 units = 192

    const v4* xb = x + ((size_t)b * T_ + (size_t)g * 8) * rs + c * (D_ / 4) + d4;

    v4 a[8];
#pragma unroll
    for (int j = 0; j < 8; ++j) a[j] = xb[(size_t)j * rs];

    v4 s2[4], m2[4];
#pragma unroll
    for (int i = 0; i < 4; ++i) {
        s2[i] = a[2*i] + a[2*i+1];
        m2[i].x = fmaxf(a[2*i].x, a[2*i+1].x);
        m2[i].y = fmaxf(a[2*i].y, a[2*i+1].y);
        m2[i].z = fmaxf(a[2*i].z, a[2*i+1].z);
        m2[i].w = fmaxf(a[2*i].w, a[2*i+1].w);
    }
    v4 s4[2], m4[2];
#pragma unroll
    for (int i = 0; i < 2; ++i) {
        s4[i] = s2[2*i] + s2[2*i+1];
        m4[i].x = fmaxf(m2[2*i].x, m2[2*i+1].x);
        m4[i].y = fmaxf(m2[2*i].y, m2[2*i+1].y);
        m4[i].z = fmaxf(m2[2*i].z, m2[2*i+1].z);
        m4[i].w = fmaxf(m2[2*i].w, m2[2*i+1].w);
    }
    v4 s8, m8;
    s8 = s4[0] + s4[1];
    m8.x = fmaxf(m4[0].x, m4[1].x);
    m8.y = fmaxf(m4[0].y, m4[1].y);
    m8.z = fmaxf(m4[0].z, m4[1].z);
    m8.w = fmaxf(m4[0].w, m4[1].w);

    v4* ob = out + (size_t)b * ML_ * rs + c * (D_ / 4) + d4;

#pragma unroll
    for (int i = 0; i < 4; ++i) {
        const int t = g * 4 + i;
        const int tu = __builtin_amdgcn_readfirstlane(t);   // wave-uniform -> s_load
        const float wv = w[tu];
        const float iw = 1.0f - wv;
        v4 r = s2[i] * (0.5f * wv) + m2[i] * iw;
        __builtin_nontemporal_store(r, &ob[(size_t)t * rs]);
    }
#pragma unroll
    for (int i = 0; i < 2; ++i) {
        const int t = 2048 + g * 2 + i;
        const int tu = __builtin_amdgcn_readfirstlane(t);
        const float wv = w[tu];
        const float iw = 1.0f - wv;
        v4 r = s4[i] * (0.25f * wv) + m4[i] * iw;
        __builtin_nontemporal_store(r, &ob[(size_t)t * rs]);
    }
    {
        const int t = 3072 + g;
        const int tu = __builtin_amdgcn_readfirstlane(t);
        const float wv = w[tu];
        const float iw = 1.0f - wv;
        v4 r = s8 * (0.125f * wv) + m8 * iw;
        __builtin_nontemporal_store(r, &ob[(size_t)t * rs]);
    }
}

extern "C" void kernel_launch(void* const* d_in, const int* in_sizes, int n_in,
                              void* d_out, int out_size, void* d_ws, size_t ws_size,
                              hipStream_t stream) {
    const v4*    x = (const v4*)d_in[0];
    const float* w = (const float*)d_in[1];
    v4* out = (v4*)d_out;

    // total threads = B * (T/8) * C * (D/4) = 8*512*3*64 = 786432 = 3072 blocks * 256
    const int nthreads = B_ * (T_ / 8) * C_ * (D_ / 4);
    const int blocks = nthreads / 256;
    multi_scale_kernel<<<blocks, 256, 0, stream>>>(x, w, out);
}